// Round 6
// baseline (31.939 us; speedup 1.0000x reference)
//
#include <hip/hip_runtime.h>
#include <stdint.h>

typedef float float4v __attribute__((ext_vector_type(4)));
typedef float float2v __attribute__((ext_vector_type(2)));

// robust criterion parse: int32, else f32, else default -1
__device__ __forceinline__ int read_crit(const void* p) {
    const int ci = *(const int*)p;
    if (ci >= -2 && ci <= 3) return ci;
    const float cf = *(const float*)p;
    if (cf == cf && fabsf(cf) <= 4.0f && cf == truncf(cf)) return (int)cf;
    return -1;
}

// Output layout (all float32):
//   [0, 4KN)     overlaps (K*N, 4)
//   [4KN, 6KN)   tensor_index (K*N, 2)  values k, n as float
//   [6KN, 7KN)   valid (K*N)            1.0 / 0.0
//
// Grid: x tiles N (one thread per box n), y tiles K in chunks of KPB.
// Each block holds its 256-box slice in registers and loops over KPB
// query boxes, so box data is read once per 10 k-rows instead of once
// per row. All stores lane-contiguous; nontemporal (streaming, no reuse).
#define KPB 10

__global__ __launch_bounds__(256) void clocs_kernel(
    const float4v* __restrict__ boxes,   // N x 4 f32
    const float4v* __restrict__ qboxes,  // K x 4 f32
    const float*   __restrict__ s3d,     // N f32
    const float*   __restrict__ s2d,     // K f32
    const float*   __restrict__ dis,     // N f32
    const void*    __restrict__ crit_p,
    float*         __restrict__ out,
    int N, int K)
{
    const int n = blockIdx.x * blockDim.x + threadIdx.x;
    if (n >= N) return;
    const int k0 = blockIdx.y * KPB;

    const int crit = read_crit(crit_p);

    // per-thread box data, registers, loaded once per block
    const float4v b  = boxes[n];
    const float   s3 = s3d[n];
    const float   dl = dis[n];
    const float barea = (b.z - b.x) * (b.w - b.y);
    const float nf = (float)n;

    const size_t KN = (size_t)K * (size_t)N;

    #pragma unroll
    for (int kk = 0; kk < KPB; ++kk) {
        const int k = k0 + kk;

        const float4v qb = qboxes[k];          // wave-uniform broadcast
        const float qarea = (qb.z - qb.x) * (qb.w - qb.y);
        const float sc2   = s2d[k];

        const float iw = fminf(b.z, qb.z) - fmaxf(b.x, qb.x);
        const float ih = fminf(b.w, qb.w) - fmaxf(b.y, qb.y);
        const bool  valid = (iw > 0.0f) && (ih > 0.0f);
        const float inter = iw * ih;
        float ua;
        if (crit == -1)      ua = barea + qarea - inter;
        else if (crit == 0)  ua = barea;
        else if (crit == 1)  ua = qarea;
        else                 ua = 1.0f;
        const float iou = (ua != 0.0f) ? (inter / ua) : 0.0f;

        float4v ov;
        ov.x = valid ? iou : -10.0f;
        ov.y = s3;
        ov.z = valid ? sc2 : -10.0f;
        ov.w = dl;

        float2v ix;
        ix.x = (float)k;
        ix.y = nf;

        const size_t p = (size_t)k * (size_t)N + (size_t)n;

        __builtin_nontemporal_store(ov, (float4v*)(out + p * 4));
        __builtin_nontemporal_store(ix, (float2v*)(out + KN * 4 + p * 2));
        __builtin_nontemporal_store(valid ? 1.0f : 0.0f, out + KN * 6 + p);
    }
}

extern "C" void kernel_launch(void* const* d_in, const int* in_sizes, int n_in,
                              void* d_out, int out_size, void* d_ws, size_t ws_size,
                              hipStream_t stream) {
    const float4v* boxes  = (const float4v*)d_in[0];
    const float4v* qboxes = (const float4v*)d_in[1];
    const float*   s3d    = (const float*)d_in[2];
    const float*   s2d    = (const float*)d_in[3];
    const float*   dis    = (const float*)d_in[4];

    const int N = in_sizes[0] / 4;   // 10000
    const int K = in_sizes[1] / 4;   // 500 (divisible by KPB=10)
    const int block = 256;
    dim3 grid((N + block - 1) / block, K / KPB, 1);

    clocs_kernel<<<grid, dim3(block, 1, 1), 0, stream>>>(
        boxes, qboxes, s3d, s2d, dis, d_in[5],
        (float*)d_out, N, K);
}

// Round 7
// 27.684 us; speedup vs baseline: 1.1537x; 1.1537x over previous
//
#include <hip/hip_runtime.h>
#include <stdint.h>

typedef float float4v __attribute__((ext_vector_type(4)));
typedef float float2v __attribute__((ext_vector_type(2)));

// robust criterion parse: int32, else f32, else default -1
__device__ __forceinline__ int read_crit(const void* p) {
    const int ci = *(const int*)p;
    if (ci >= -2 && ci <= 3) return ci;
    const float cf = *(const float*)p;
    if (cf == cf && fabsf(cf) <= 4.0f && cf == truncf(cf)) return (int)cf;
    return -1;
}

// Output layout (all float32):
//   [0, 4KN)     overlaps (K*N, 4)
//   [4KN, 6KN)   tensor_index (K*N, 2)  values k, n as float
//   [6KN, 7KN)   valid (K*N)            1.0 / 0.0
//
// Grid: x tiles N (one thread per box n), y tiles K in chunks of KPB.
// Box data held in registers across KPB k-rows. All stores lane-contiguous.
// PLAIN stores (round 6 showed nontemporal + strided k-walk scatters HBM
// write order and costs 18%).
#define KPB 10

__global__ __launch_bounds__(256) void clocs_kernel(
    const float4v* __restrict__ boxes,   // N x 4 f32
    const float4v* __restrict__ qboxes,  // K x 4 f32
    const float*   __restrict__ s3d,     // N f32
    const float*   __restrict__ s2d,     // K f32
    const float*   __restrict__ dis,     // N f32
    const void*    __restrict__ crit_p,
    float*         __restrict__ out,
    int N, int K)
{
    const int n = blockIdx.x * blockDim.x + threadIdx.x;
    if (n >= N) return;
    const int k0 = blockIdx.y * KPB;

    const int crit = read_crit(crit_p);

    // per-thread box data, registers, loaded once per block
    const float4v b  = boxes[n];
    const float   s3 = s3d[n];
    const float   dl = dis[n];
    const float barea = (b.z - b.x) * (b.w - b.y);
    const float nf = (float)n;

    const size_t KN = (size_t)K * (size_t)N;

    #pragma unroll
    for (int kk = 0; kk < KPB; ++kk) {
        const int k = k0 + kk;

        const float4v qb = qboxes[k];          // wave-uniform broadcast
        const float qarea = (qb.z - qb.x) * (qb.w - qb.y);
        const float sc2   = s2d[k];

        const float iw = fminf(b.z, qb.z) - fmaxf(b.x, qb.x);
        const float ih = fminf(b.w, qb.w) - fmaxf(b.y, qb.y);
        const bool  valid = (iw > 0.0f) && (ih > 0.0f);
        const float inter = iw * ih;
        float ua;
        if (crit == -1)      ua = barea + qarea - inter;
        else if (crit == 0)  ua = barea;
        else if (crit == 1)  ua = qarea;
        else                 ua = 1.0f;
        const float iou = (ua != 0.0f) ? (inter / ua) : 0.0f;

        float4v ov;
        ov.x = valid ? iou : -10.0f;
        ov.y = s3;
        ov.z = valid ? sc2 : -10.0f;
        ov.w = dl;

        float2v ix;
        ix.x = (float)k;
        ix.y = nf;

        const size_t p = (size_t)k * (size_t)N + (size_t)n;

        *(float4v*)(out + p * 4)          = ov;
        *(float2v*)(out + KN * 4 + p * 2) = ix;
        *(out + KN * 6 + p)               = valid ? 1.0f : 0.0f;
    }
}

extern "C" void kernel_launch(void* const* d_in, const int* in_sizes, int n_in,
                              void* d_out, int out_size, void* d_ws, size_t ws_size,
                              hipStream_t stream) {
    const float4v* boxes  = (const float4v*)d_in[0];
    const float4v* qboxes = (const float4v*)d_in[1];
    const float*   s3d    = (const float*)d_in[2];
    const float*   s2d    = (const float*)d_in[3];
    const float*   dis    = (const float*)d_in[4];

    const int N = in_sizes[0] / 4;   // 10000
    const int K = in_sizes[1] / 4;   // 500 (divisible by KPB=10)
    const int block = 256;
    dim3 grid((N + block - 1) / block, K / KPB, 1);

    clocs_kernel<<<grid, dim3(block, 1, 1), 0, stream>>>(
        boxes, qboxes, s3d, s2d, dis, d_in[5],
        (float*)d_out, N, K);
}